// Round 8
// baseline (197.167 us; speedup 1.0000x reference)
//
#include <hip/hip_runtime.h>

// ALiBi bias subtraction: out[b,h,i,j] = scores[b,h,i,j] - slope(h)*(i-j)
// (offset cancels in pos_diff). B=2, H=16, S=2048 -> shift/mask index decomp.
// v8: same flat no-loop 4-deep contiguous MLP as v7 (185.4us, 5.8 TB/s), but
// 512-thread blocks (grid 16384, 64 KiB/block) to halve dispatch events.
// If neutral -> practical r+w roofline reached.

typedef float f32x4 __attribute__((ext_vector_type(4)));

__device__ __forceinline__ f32x4 alibi_apply(f32x4 s, unsigned int idx4) {
    const unsigned int e = idx4 << 2;              // element index of lane's .x
    const int j = (int)(e & 2047u);                // S = 2048
    const int i = (int)((e >> 11) & 2047u);
    const int h = (int)((e >> 22) & 15u);          // H = 16
    const float slope = exp2f(-0.5f * (float)(h + 1));  // 2^(-8*(h+1)/16)
    const int d = i - j;
    f32x4 o;
    o.x = s.x - slope * (float)(d);
    o.y = s.y - slope * (float)(d - 1);
    o.z = s.z - slope * (float)(d - 2);
    o.w = s.w - slope * (float)(d - 3);
    return o;
}

__global__ __launch_bounds__(512) void alibi_kernel(const f32x4* __restrict__ in,
                                                    f32x4* __restrict__ out,
                                                    unsigned int n4) {
    // One contiguous 64 KiB chunk (4*512 float4s) per block; no loop.
    const unsigned int base = blockIdx.x * 2048u + threadIdx.x;
    if (base + 1536u >= n4) {  // guard (never taken for the bench shape)
        for (unsigned int k = 0; k < 4u; ++k) {
            unsigned int idx = base + k * 512u;
            if (idx < n4) out[idx] = alibi_apply(in[idx], idx);
        }
        return;
    }
    f32x4 s0 = in[base];
    f32x4 s1 = in[base + 512u];
    f32x4 s2 = in[base + 1024u];
    f32x4 s3 = in[base + 1536u];
    out[base]          = alibi_apply(s0, base);
    out[base + 512u]   = alibi_apply(s1, base + 512u);
    out[base + 1024u]  = alibi_apply(s2, base + 1024u);
    out[base + 1536u]  = alibi_apply(s3, base + 1536u);
}

extern "C" void kernel_launch(void* const* d_in, const int* in_sizes, int n_in,
                              void* d_out, int out_size, void* d_ws, size_t ws_size,
                              hipStream_t stream) {
    const f32x4* in = (const f32x4*)d_in[0];
    f32x4* out = (f32x4*)d_out;
    const unsigned int n4 = (unsigned int)(out_size / 4);  // 33554432 float4s
    const int block = 512;
    const int grid = (int)((n4 + 2047u) / 2048u);  // 16384: one 64-KiB chunk per block
    alibi_kernel<<<grid, block, 0, stream>>>(in, out, n4);
}

// Round 9
// 187.768 us; speedup vs baseline: 1.0501x; 1.0501x over previous
//
#include <hip/hip_runtime.h>

// ALiBi bias subtraction: out[b,h,i,j] = scores[b,h,i,j] - slope(h)*(i-j)
// (offset cancels in pos_diff). B=2, H=16, S=2048 -> shift/mask index decomp.
// v9 = v7 (best: 185.4us, 5.79 TB/s effective r+w = 92% of copy ceiling).
// Flat no-loop launch: one contiguous 16 KiB chunk per 256-thread block,
// 4 independent loads in flight per thread (4-deep MLP), plain loads/stores.
// Tested and rejected: NT hints (neutral), 8-deep MLP (neutral-), strided
// unroll (-10%, HBM channel aliasing), grid-stride loop (-8%), 512-thread
// blocks (-6%).

typedef float f32x4 __attribute__((ext_vector_type(4)));

__device__ __forceinline__ f32x4 alibi_apply(f32x4 s, unsigned int idx4) {
    const unsigned int e = idx4 << 2;              // element index of lane's .x
    const int j = (int)(e & 2047u);                // S = 2048
    const int i = (int)((e >> 11) & 2047u);
    const int h = (int)((e >> 22) & 15u);          // H = 16
    const float slope = exp2f(-0.5f * (float)(h + 1));  // 2^(-8*(h+1)/16)
    const int d = i - j;
    f32x4 o;
    o.x = s.x - slope * (float)(d);
    o.y = s.y - slope * (float)(d - 1);
    o.z = s.z - slope * (float)(d - 2);
    o.w = s.w - slope * (float)(d - 3);
    return o;
}

__global__ __launch_bounds__(256) void alibi_kernel(const f32x4* __restrict__ in,
                                                    f32x4* __restrict__ out,
                                                    unsigned int n4) {
    // One contiguous 16 KiB chunk (4*256 float4s) per block; no loop.
    const unsigned int base = blockIdx.x * 1024u + threadIdx.x;
    if (base + 768u >= n4) {  // guard (never taken for the bench shape)
        for (unsigned int k = 0; k < 4u; ++k) {
            unsigned int idx = base + k * 256u;
            if (idx < n4) out[idx] = alibi_apply(in[idx], idx);
        }
        return;
    }
    f32x4 s0 = in[base];
    f32x4 s1 = in[base + 256u];
    f32x4 s2 = in[base + 512u];
    f32x4 s3 = in[base + 768u];
    out[base]         = alibi_apply(s0, base);
    out[base + 256u]  = alibi_apply(s1, base + 256u);
    out[base + 512u]  = alibi_apply(s2, base + 512u);
    out[base + 768u]  = alibi_apply(s3, base + 768u);
}

extern "C" void kernel_launch(void* const* d_in, const int* in_sizes, int n_in,
                              void* d_out, int out_size, void* d_ws, size_t ws_size,
                              hipStream_t stream) {
    const f32x4* in = (const f32x4*)d_in[0];
    f32x4* out = (f32x4*)d_out;
    const unsigned int n4 = (unsigned int)(out_size / 4);  // 33554432 float4s
    const int block = 256;
    const int grid = (int)((n4 + 1023u) / 1024u);  // 32768: one 16-KiB chunk per block
    alibi_kernel<<<grid, block, 0, stream>>>(in, out, n4);
}